// Round 6
// baseline (1681.475 us; speedup 1.0000x reference)
//
#include <hip/hip_runtime.h>
#include <cstdint>

#define BB 4
#define NN 20000
#define CC 512
#define MM 1024
#define GTHR 0.1f
#define FPS_T 1024
#define NW (FPS_T / 64)  // 16 waves
#define LDSCAP 5120      // max compacted points held in LDS
#define QB 8

#define INFF __builtin_huge_valf()
typedef unsigned long long u64;

// ---------------------------------------------------------------------------
// All-lane wave max of a u64 key ((dist_bits<<32)|~j): 4 DPP row_ror steps
// (windows 2/4/8/16 within rows of 16) + ds_swizzle xor16 + shfl_xor 32.
// Exact; every lane ends with the global max. No branches, no ballot.
// ---------------------------------------------------------------------------
#define DPP_MAX_STEP(CTRL)                                                  \
  {                                                                         \
    unsigned lo = (unsigned)k, hi = (unsigned)(k >> 32);                    \
    int ol = __builtin_amdgcn_update_dpp((int)lo, (int)lo, CTRL, 0xF, 0xF,  \
                                         false);                            \
    int oh = __builtin_amdgcn_update_dpp((int)hi, (int)hi, CTRL, 0xF, 0xF,  \
                                         false);                            \
    u64 o = ((u64)(unsigned)oh << 32) | (unsigned)ol;                       \
    k = o > k ? o : k;                                                      \
  }

__device__ __forceinline__ u64 wave_max_u64(u64 k) {
  DPP_MAX_STEP(0x121)  // row_ror:1
  DPP_MAX_STEP(0x122)  // row_ror:2
  DPP_MAX_STEP(0x124)  // row_ror:4
  DPP_MAX_STEP(0x128)  // row_ror:8 -> each lane has its row-of-16 max
  {  // xor16 within each 32-lane half
    unsigned lo = (unsigned)k, hi = (unsigned)(k >> 32);
    int ol = __builtin_amdgcn_ds_swizzle((int)lo, 0x401F);
    int oh = __builtin_amdgcn_ds_swizzle((int)hi, 0x401F);
    u64 o = ((u64)(unsigned)oh << 32) | (unsigned)ol;
    k = o > k ? o : k;
  }
  {  // cross the 32-lane halves
    u64 o = __shfl_xor(k, 32);
    k = o > k ? o : k;
  }
  return k;
}

// 16-candidate u64 max -> winner's compacted index (tree, broadcast reads)
__device__ __forceinline__ unsigned merge16(const u64* pkrow) {
  const ulonglong2* p2 = (const ulonglong2*)pkrow;
  ulonglong2 e0 = p2[0], e1 = p2[1], e2 = p2[2], e3 = p2[3];
  ulonglong2 e4 = p2[4], e5 = p2[5], e6 = p2[6], e7 = p2[7];
  u64 a = e0.x > e0.y ? e0.x : e0.y;
  u64 b = e1.x > e1.y ? e1.x : e1.y;
  u64 c = e2.x > e2.y ? e2.x : e2.y;
  u64 d = e3.x > e3.y ? e3.x : e3.y;
  u64 e = e4.x > e4.y ? e4.x : e4.y;
  u64 f = e5.x > e5.y ? e5.x : e5.y;
  u64 g = e6.x > e6.y ? e6.x : e6.y;
  u64 h = e7.x > e7.y ? e7.x : e7.y;
  a = a > b ? a : b;
  c = c > d ? c : d;
  e = e > f ? e : f;
  g = g > h ? g : h;
  a = a > c ? a : c;
  e = e > g ? e : g;
  a = a > e ? a : e;
  return ~(unsigned)(a & 0xffffffffull);
}

// ---------------------------------------------------------------------------
// FPS main path: compacted cloud in LDS, slots in registers, zero global ops
// inside the loop. Winner of iteration r is latched by thread t==r and all
// M coordinates are written once at the end.
// ---------------------------------------------------------------------------
template <int K>
__device__ void fps_lds(int nv_, const float2* lxy, const float* lz,
                        float4* fpsXyzb, u64 (*pk)[NW]) {
  const int t = threadIdx.x;
  const int lane = t & 63, w = t >> 6;
  float x[K], y[K], z[K], mind[K];
#pragma unroll
  for (int s = 0; s < K; ++s) {
    int j = s * FPS_T + t;
    if (j < nv_) {
      float2 p = lxy[j];
      x[s] = p.x; y[s] = p.y; z[s] = lz[j]; mind[s] = INFF;
    } else {
      // invalid slot: mind pinned 0 -> only matches when global max is 0 and
      // then loses the min-index tie-break (fake j >= nv_ > any real j).
      x[s] = 0.f; y[s] = 0.f; z[s] = 0.f; mind[s] = 0.f;
    }
  }
  float qx = lxy[0].x, qy = lxy[0].y, qz = lz[0];  // first pick = compacted 0
  unsigned jsave = 0;  // thread t holds winner of iteration r==t (t=0 -> 0)
  int buf = 0;
  for (int r = 1; r < MM; ++r) {
    float bm = -1.f;
    int bs = 0;
#pragma unroll
    for (int s = 0; s < K; ++s) {
      float dx = x[s] - qx, dy = y[s] - qy, dz = z[s] - qz;
      float d = fmaf(dz, dz, fmaf(dy, dy, dx * dx));
      float m = fminf(mind[s], d);
      mind[s] = m;
      bool better = m > bm;  // strict >: smallest slot (smallest j) on ties
      bm = better ? m : bm;
      bs = better ? s : bs;
    }
    unsigned j = (unsigned)(bs * FPS_T + t);
    u64 key = ((u64)__float_as_uint(bm) << 32) | (unsigned)(~j);
    key = wave_max_u64(key);
    if (lane == 0) pk[buf][w] = key;
    __syncthreads();
    unsigned jg = merge16(&pk[buf][0]);  // global winner (max dist, min j)
    float2 qq = lxy[jg];
    qx = qq.x; qy = qq.y; qz = lz[jg];
    if (r == (unsigned)t) jsave = jg;
    buf ^= 1;
  }
  float2 pp = lxy[jsave];
  fpsXyzb[t] = make_float4(pp.x, pp.y, lz[jsave], 0.f);
}

// Correct-but-slow path for nv > LDSCAP (practically unreachable: nv~4600).
__device__ void fps_fallback(int nv_, const float4* cxg, float4* fpsXyzb,
                             float* mindg, u64 (*pk)[NW]) {
  const int t = threadIdx.x;
  const int lane = t & 63, w = t >> 6;
  for (int j = t; j < nv_; j += FPS_T) mindg[j] = INFF;
  __syncthreads();
  float4 q = cxg[0];
  float qx = q.x, qy = q.y, qz = q.z;
  unsigned jsave = 0;
  int buf = 0;
  for (int r = 1; r < MM; ++r) {
    float bm = -1.f;
    int bj = 0x7fffffff;
    for (int j = t; j < nv_; j += FPS_T) {
      float4 p = cxg[j];
      float dx = p.x - qx, dy = p.y - qy, dz = p.z - qz;
      float d = fmaf(dz, dz, fmaf(dy, dy, dx * dx));
      float m = fminf(mindg[j], d);
      mindg[j] = m;
      bool better = m > bm;  // j ascending within lane: keeps smallest j
      bm = better ? m : bm;
      bj = better ? j : bj;
    }
    u64 key = ((u64)__float_as_uint(bm) << 32) | (unsigned)(~(unsigned)bj);
    key = wave_max_u64(key);
    if (lane == 0) pk[buf][w] = key;
    __syncthreads();
    unsigned jg = merge16(&pk[buf][0]);
    float4 qq = cxg[jg];
    qx = qq.x; qy = qq.y; qz = qq.z;
    if (r == (unsigned)t) jsave = jg;
    buf ^= 1;
  }
  float4 pp = cxg[jsave];
  fpsXyzb[t] = pp;
}

// ---------------------------------------------------------------------------
// Fused compaction + FPS: one block per batch, 1024 threads (16 waves).
// Wave w owns span [w*1250, (w+1)*1250) so compaction preserves point order.
// ---------------------------------------------------------------------------
__global__ __launch_bounds__(FPS_T) void fps_kernel(
    const float* __restrict__ pc, const float* __restrict__ obj,
    const float* __restrict__ grasp, float4* __restrict__ fpsXyz,
    float4* __restrict__ cxyz_g, float* __restrict__ mindg) {
  __shared__ float2 lxy[LDSCAP];
  __shared__ float lz[LDSCAP];
  __shared__ alignas(16) u64 pk[2][NW];
  __shared__ int wtot[NW];
  const int b = blockIdx.x;
  const int t = threadIdx.x;
  const int lane = t & 63, w = t >> 6;
  const float* pcb = pc + (size_t)b * NN * 3;
  const float* o0 = obj + (size_t)b * 2 * NN;
  const float* o1 = o0 + NN;
  const float* gb = grasp + (size_t)b * NN;
  float4* fpsXyzb = fpsXyz + (size_t)b * MM;
  float4* cxg = cxyz_g + (size_t)b * NN;

  // ---- pass 1: validity bits + per-wave counts ----
  const int SPAN = 1250;  // 16 waves * 1250 = 20000
  const int wstart = w * SPAN;
  unsigned vmask = 0;  // 20 group bits
  int cnt = 0;
#pragma unroll
  for (int g = 0; g < 20; ++g) {
    int off = g * 64 + lane;
    bool v = false;
    if (off < SPAN) {
      int i = wstart + off;
      // argmax(axis=1)==1  <=>  o1 > o0 strictly (argmax picks first max)
      v = (o1[i] > o0[i]) && (gb[i] > GTHR);
    }
    u64 bal = __ballot(v);
    if (v) vmask |= (1u << g);
    cnt += (int)__popcll(bal);
  }
  if (lane == 0) wtot[w] = cnt;
  __syncthreads();
  int base = 0, nv_ = 0;
#pragma unroll
  for (int k = 0; k < NW; ++k) {
    int c = wtot[k];
    if (k < w) base += c;
    nv_ += c;
  }
  const bool useg = (nv_ > LDSCAP);
  // ---- pass 2: scatter compacted coords ----
#pragma unroll
  for (int g = 0; g < 20; ++g) {
    bool v = (vmask >> g) & 1u;
    u64 bal = __ballot(v);
    if (v) {
      int i = wstart + g * 64 + lane;
      float xx = pcb[3 * i], yy = pcb[3 * i + 1], zz = pcb[3 * i + 2];
      int pos = base + (int)__popcll(bal & ((1ull << lane) - 1ull));
      if (pos < LDSCAP) { lxy[pos] = make_float2(xx, yy); lz[pos] = zz; }
      if (useg) cxg[pos] = make_float4(xx, yy, zz, 0.f);
    }
    base += (int)__popcll(bal);
  }
  __syncthreads();

  if (nv_ == 0) {  // reference: argmax over all -inf = index 0 every step
    float4 p0 = make_float4(pcb[0], pcb[1], pcb[2], 0.f);
    for (int r = t; r < MM; r += FPS_T) fpsXyzb[r] = p0;
    return;
  }
  int slots = (nv_ + FPS_T - 1) / FPS_T;
  if (slots <= 2)      fps_lds<2>(nv_, lxy, lz, fpsXyzb, pk);
  else if (slots <= 3) fps_lds<3>(nv_, lxy, lz, fpsXyzb, pk);
  else if (slots <= 4) fps_lds<4>(nv_, lxy, lz, fpsXyzb, pk);
  else if (slots <= 5) fps_lds<5>(nv_, lxy, lz, fpsXyzb, pk);
  else fps_fallback(nv_, cxg, fpsXyzb, mindg + (size_t)b * NN, pk);
}

// ---------------------------------------------------------------------------
// three_nn (8 queries per 256-thread block) + inverse-distance weights
// ---------------------------------------------------------------------------
__device__ __forceinline__ bool nn_before(float ad, int ai, float bd, int bi) {
  return (ad < bd) || (ad == bd && ai < bi);  // stable ascending (top_k)
}

__device__ __forceinline__ void merge3(float* ad, int* ai,
                                       float b0, float b1, float b2,
                                       int j0, int j1, int j2) {
  bool c0 = nn_before(ad[0], ai[0], b0, j0);
  float r0d = c0 ? ad[0] : b0; int r0i = c0 ? ai[0] : j0;
  float Xd = c0 ? b0 : ad[0];  int Xi = c0 ? j0 : ai[0];
  bool c1 = nn_before(ad[1], ai[1], b1, j1);
  float Yd = c1 ? ad[1] : b1;  int Yi = c1 ? ai[1] : j1;
  bool c2 = nn_before(Xd, Xi, Yd, Yi);
  float r1d = c2 ? Xd : Yd;    int r1i = c2 ? Xi : Yi;
  float Wd = c2 ? Yd : Xd;     int Wi = c2 ? Yi : Xi;
  bool c3 = nn_before(ad[2], ai[2], b2, j2);
  float Vd = c3 ? ad[2] : b2;  int Vi = c3 ? ai[2] : j2;
  bool c4 = nn_before(Wd, Wi, Vd, Vi);
  float r2d = c4 ? Wd : Vd;    int r2i = c4 ? Wi : Vi;
  ad[0] = r0d; ad[1] = r1d; ad[2] = r2d;
  ai[0] = r0i; ai[1] = r1i; ai[2] = r2i;
}

__global__ void three_nn_kernel(const float* __restrict__ pc,
                                const float4* __restrict__ fpsXyz,
                                int* __restrict__ idx3,
                                float* __restrict__ w3) {
  const int blk = blockIdx.x;
  const int b = blk / (MM / QB);
  const int qbase = (blk % (MM / QB)) * QB;
  const int t = threadIdx.x;
  const int lane = t & 63, w = t >> 6;
  const float* pcb = pc + (size_t)b * NN * 3;
  float qx[QB], qy[QB], qz[QB];
#pragma unroll
  for (int qq = 0; qq < QB; ++qq) {
    float4 p = fpsXyz[(size_t)b * MM + qbase + qq];
    qx[qq] = p.x; qy[qq] = p.y; qz[qq] = p.z;
  }
  float qd[QB][3]; int qi[QB][3];
#pragma unroll
  for (int qq = 0; qq < QB; ++qq)
#pragma unroll
    for (int k = 0; k < 3; ++k) { qd[qq][k] = INFF; qi[qq][k] = 0x7fffffff; }

  const int nchunk = (NN + 255) / 256;
  for (int c = 0; c < nchunk; ++c) {
    int i = c * 256 + t;
    if (i < NN) {
      float pxx = pcb[3 * i], pyy = pcb[3 * i + 1], pzz = pcb[3 * i + 2];
#pragma unroll
      for (int qq = 0; qq < QB; ++qq) {
        float dx = pxx - qx[qq], dy = pyy - qy[qq], dz = pzz - qz[qq];
        float d = fmaf(dz, dz, fmaf(dy, dy, dx * dx));
        if (d < qd[qq][2]) {
          bool lt0 = d < qd[qq][0], lt1 = d < qd[qq][1];
          qd[qq][2] = lt1 ? qd[qq][1] : d;  qi[qq][2] = lt1 ? qi[qq][1] : i;
          float nd1 = lt0 ? qd[qq][0] : (lt1 ? d : qd[qq][1]);
          int   ni1 = lt0 ? qi[qq][0] : (lt1 ? i : qi[qq][1]);
          qd[qq][1] = nd1; qi[qq][1] = ni1;
          qd[qq][0] = lt0 ? d : qd[qq][0];  qi[qq][0] = lt0 ? i : qi[qq][0];
        }
      }
    }
  }
#pragma unroll
  for (int off = 32; off; off >>= 1) {
#pragma unroll
    for (int qq = 0; qq < QB; ++qq) {
      float bd0 = __shfl_xor(qd[qq][0], off);
      float bd1 = __shfl_xor(qd[qq][1], off);
      float bd2 = __shfl_xor(qd[qq][2], off);
      int bi0 = __shfl_xor(qi[qq][0], off);
      int bi1 = __shfl_xor(qi[qq][1], off);
      int bi2 = __shfl_xor(qi[qq][2], off);
      merge3(qd[qq], qi[qq], bd0, bd1, bd2, bi0, bi1, bi2);
    }
  }
  __shared__ float smd[4][QB][3];
  __shared__ int smi[4][QB][3];
  if (lane == 0) {
#pragma unroll
    for (int qq = 0; qq < QB; ++qq)
#pragma unroll
      for (int k = 0; k < 3; ++k) { smd[w][qq][k] = qd[qq][k]; smi[w][qq][k] = qi[qq][k]; }
  }
  __syncthreads();
  if (t < QB) {
    int qq = t;
    float fd[3]; int fi[3];
#pragma unroll
    for (int k = 0; k < 3; ++k) { fd[k] = smd[0][qq][k]; fi[k] = smi[0][qq][k]; }
#pragma unroll
    for (int ww = 1; ww < 4; ++ww)
      merge3(fd, fi, smd[ww][qq][0], smd[ww][qq][1], smd[ww][qq][2],
             smi[ww][qq][0], smi[ww][qq][1], smi[ww][qq][2]);
    float wa = 1.f / (sqrtf(fmaxf(fd[0], 0.f)) + 1e-8f);
    float wb = 1.f / (sqrtf(fmaxf(fd[1], 0.f)) + 1e-8f);
    float wc = 1.f / (sqrtf(fmaxf(fd[2], 0.f)) + 1e-8f);
    float s = wa + wb + wc;
    size_t base3 = ((size_t)b * MM + qbase + qq) * 3;
    w3[base3] = wa / s; w3[base3 + 1] = wb / s; w3[base3 + 2] = wc / s;
    idx3[base3] = fi[0]; idx3[base3 + 1] = fi[1]; idx3[base3 + 2] = fi[2];
  }
}

// ---------------------------------------------------------------------------
// three_interpolate (one block per (b,c) feature row)
// ---------------------------------------------------------------------------
__global__ void interp_kernel(const float* __restrict__ seed,
                              const int* __restrict__ idx3,
                              const float* __restrict__ w3,
                              float* __restrict__ out) {
  const int blk = blockIdx.x;
  const int b = blk / CC;
  const int c = blk % CC;
  const float* row = seed + ((size_t)b * CC + c) * NN;
  const int t = threadIdx.x;
#pragma unroll
  for (int u = 0; u < MM / 256; ++u) {
    int m = u * 256 + t;
    size_t base3 = ((size_t)b * MM + m) * 3;
    int i0 = idx3[base3], i1 = idx3[base3 + 1], i2 = idx3[base3 + 2];
    float w0 = w3[base3], w1 = w3[base3 + 1], w2 = w3[base3 + 2];
    float v = fmaf(w2, row[i2], fmaf(w1, row[i1], w0 * row[i0]));
    out[((size_t)b * CC + c) * MM + m] = v;
  }
}

// ---------------------------------------------------------------------------
extern "C" void kernel_launch(void* const* d_in, const int* in_sizes, int n_in,
                              void* d_out, int out_size, void* d_ws,
                              size_t ws_size, hipStream_t stream) {
  (void)in_sizes; (void)n_in; (void)out_size; (void)ws_size;
  const float* pc = (const float*)d_in[0];     // (B,N,3)
  const float* seed = (const float*)d_in[1];   // (B,C,N)
  const float* obj = (const float*)d_in[2];    // (B,2,N)
  const float* grasp = (const float*)d_in[3];  // (B,N)
  float* out = (float*)d_out;                  // (B,C,M)

  char* p = (char*)d_ws;
  float4* cxyz = (float4*)p;   p += sizeof(float4) * BB * NN;
  float4* fpsXyz = (float4*)p; p += sizeof(float4) * BB * MM;
  int* idx3 = (int*)p;         p += sizeof(int) * BB * MM * 3;
  float* w3 = (float*)p;       p += sizeof(float) * BB * MM * 3;
  float* mindg = (float*)p;    p += sizeof(float) * BB * NN;

  hipLaunchKernelGGL(fps_kernel, dim3(BB), dim3(FPS_T), 0, stream,
                     pc, obj, grasp, fpsXyz, cxyz, mindg);
  hipLaunchKernelGGL(three_nn_kernel, dim3(BB * MM / QB), dim3(256), 0, stream,
                     pc, fpsXyz, idx3, w3);
  hipLaunchKernelGGL(interp_kernel, dim3(BB * CC), dim3(256), 0, stream,
                     seed, idx3, w3, out);
}

// Round 7
// 1210.769 us; speedup vs baseline: 1.3888x; 1.3888x over previous
//
#include <hip/hip_runtime.h>
#include <cstdint>

#define BB 4
#define NN 20000
#define CC 512
#define MM 1024
#define GTHR 0.1f
#define FPS_T 512
#define NW (FPS_T / 64)  // 8 waves
#define LDSCAP 5120      // max compacted points held in LDS (= 10 slots)
#define QB 8

#define INFF __builtin_huge_valf()
typedef unsigned long long u64;

// ---------------------------------------------------------------------------
// All-lane wave max of a u64 key ((dist_bits<<32)|~j): 4 DPP row_ror steps
// within rows of 16, then ds_swizzle xor16, then shfl_xor 32. Exact, no
// branches; every lane ends with the wave max. (Validated rounds 5/6.)
// ---------------------------------------------------------------------------
#define DPP_MAX_STEP(CTRL)                                                  \
  {                                                                         \
    unsigned lo = (unsigned)k, hi = (unsigned)(k >> 32);                    \
    int ol = __builtin_amdgcn_update_dpp((int)lo, (int)lo, CTRL, 0xF, 0xF,  \
                                         false);                            \
    int oh = __builtin_amdgcn_update_dpp((int)hi, (int)hi, CTRL, 0xF, 0xF,  \
                                         false);                            \
    u64 o = ((u64)(unsigned)oh << 32) | (unsigned)ol;                       \
    k = o > k ? o : k;                                                      \
  }

__device__ __forceinline__ u64 wave_max_u64(u64 k) {
  DPP_MAX_STEP(0x121)  // row_ror:1
  DPP_MAX_STEP(0x122)  // row_ror:2
  DPP_MAX_STEP(0x124)  // row_ror:4
  DPP_MAX_STEP(0x128)  // row_ror:8 -> each lane has its row-of-16 max
  {  // xor16 within each 32-lane half
    unsigned lo = (unsigned)k, hi = (unsigned)(k >> 32);
    int ol = __builtin_amdgcn_ds_swizzle((int)lo, 0x401F);
    int oh = __builtin_amdgcn_ds_swizzle((int)hi, 0x401F);
    u64 o = ((u64)(unsigned)oh << 32) | (unsigned)ol;
    k = o > k ? o : k;
  }
  {  // cross the 32-lane halves
    u64 o = __shfl_xor(k, 32);
    k = o > k ? o : k;
  }
  return k;
}

// 8-candidate u64 max -> winner's compacted index (broadcast reads + tree).
// (Validated round 5.)
__device__ __forceinline__ unsigned merge8(const u64* pkrow) {
  const ulonglong2* p2 = (const ulonglong2*)pkrow;
  ulonglong2 e0 = p2[0], e1 = p2[1], e2 = p2[2], e3 = p2[3];
  u64 a = e0.x > e0.y ? e0.x : e0.y;
  u64 b = e1.x > e1.y ? e1.x : e1.y;
  u64 c = e2.x > e2.y ? e2.x : e2.y;
  u64 d = e3.x > e3.y ? e3.x : e3.y;
  a = a > b ? a : b;
  c = c > d ? c : d;
  a = a > c ? a : c;
  return ~(unsigned)(a & 0xffffffffull);
}

// ---------------------------------------------------------------------------
// FPS main path: compacted cloud in LDS, slots in registers, zero global ops
// inside the loop. Thread t latches the winners of iterations t and t+512;
// all M coordinates are written once at the end.
// ---------------------------------------------------------------------------
template <int K>
__device__ void fps_lds(int nv_, const float2* lxy, const float* lz,
                        float4* fpsXyzb, u64 (*pk)[NW]) {
  const int t = threadIdx.x;
  const int lane = t & 63, w = t >> 6;
  float x[K], y[K], z[K], mind[K];
#pragma unroll
  for (int s = 0; s < K; ++s) {
    int j = s * FPS_T + t;
    if (j < nv_) {
      float2 p = lxy[j];
      x[s] = p.x; y[s] = p.y; z[s] = lz[j]; mind[s] = INFF;
    } else {
      // invalid slot: mind pinned 0 -> only matches when global max is 0 and
      // then loses the min-index tie-break (fake j >= nv_ > any real j).
      x[s] = 0.f; y[s] = 0.f; z[s] = 0.f; mind[s] = 0.f;
    }
  }
  float qx = lxy[0].x, qy = lxy[0].y, qz = lz[0];  // first pick = compacted 0
  unsigned jsaveA = 0, jsaveB = 0;  // winners of iterations t and t+FPS_T
  int buf = 0;
  for (int r = 1; r < MM; ++r) {
    float bm = -1.f;
    int bs = 0;
#pragma unroll
    for (int s = 0; s < K; ++s) {
      float dx = x[s] - qx, dy = y[s] - qy, dz = z[s] - qz;
      float d = fmaf(dz, dz, fmaf(dy, dy, dx * dx));
      float m = fminf(mind[s], d);
      mind[s] = m;
      bool better = m > bm;  // strict >: smallest slot (smallest j) on ties
      bm = better ? m : bm;
      bs = better ? s : bs;
    }
    unsigned j = (unsigned)(bs * FPS_T + t);
    u64 key = ((u64)__float_as_uint(bm) << 32) | (unsigned)(~j);
    key = wave_max_u64(key);
    if (lane == 0) pk[buf][w] = key;
    __syncthreads();
    unsigned jg = merge8(&pk[buf][0]);  // global winner (max dist, min j)
    float2 qq = lxy[jg];
    qx = qq.x; qy = qq.y; qz = lz[jg];
    if (r == t) jsaveA = jg;
    if (r == t + FPS_T) jsaveB = jg;
    buf ^= 1;
  }
  float2 pa = lxy[jsaveA];
  fpsXyzb[t] = make_float4(pa.x, pa.y, lz[jsaveA], 0.f);
  float2 pb = lxy[jsaveB];
  fpsXyzb[t + FPS_T] = make_float4(pb.x, pb.y, lz[jsaveB], 0.f);
}

// Correct-but-slow path for nv > LDSCAP (practically unreachable: nv~4600).
__device__ void fps_fallback(int nv_, const float4* cxg, float4* fpsXyzb,
                             float* mindg, u64 (*pk)[NW]) {
  const int t = threadIdx.x;
  const int lane = t & 63, w = t >> 6;
  for (int j = t; j < nv_; j += FPS_T) mindg[j] = INFF;
  __syncthreads();
  float4 q = cxg[0];
  float qx = q.x, qy = q.y, qz = q.z;
  unsigned jsaveA = 0, jsaveB = 0;
  int buf = 0;
  for (int r = 1; r < MM; ++r) {
    float bm = -1.f;
    int bj = 0x7fffffff;
    for (int j = t; j < nv_; j += FPS_T) {
      float4 p = cxg[j];
      float dx = p.x - qx, dy = p.y - qy, dz = p.z - qz;
      float d = fmaf(dz, dz, fmaf(dy, dy, dx * dx));
      float m = fminf(mindg[j], d);
      mindg[j] = m;
      bool better = m > bm;  // j ascending within lane: keeps smallest j
      bm = better ? m : bm;
      bj = better ? j : bj;
    }
    u64 key = ((u64)__float_as_uint(bm) << 32) | (unsigned)(~(unsigned)bj);
    key = wave_max_u64(key);
    if (lane == 0) pk[buf][w] = key;
    __syncthreads();
    unsigned jg = merge8(&pk[buf][0]);
    float4 qq = cxg[jg];
    qx = qq.x; qy = qq.y; qz = qq.z;
    if (r == t) jsaveA = jg;
    if (r == t + FPS_T) jsaveB = jg;
    buf ^= 1;
  }
  fpsXyzb[t] = cxg[jsaveA];
  fpsXyzb[t + FPS_T] = cxg[jsaveB];
}

// ---------------------------------------------------------------------------
// Fused compaction + FPS: one block per batch, 512 threads (8 waves).
// Wave w owns span [w*2500, (w+1)*2500) so compaction preserves point order.
// (Compaction section validated round 5.)
// ---------------------------------------------------------------------------
__global__ __launch_bounds__(FPS_T) void fps_kernel(
    const float* __restrict__ pc, const float* __restrict__ obj,
    const float* __restrict__ grasp, float4* __restrict__ fpsXyz,
    float4* __restrict__ cxyz_g, float* __restrict__ mindg) {
  __shared__ float2 lxy[LDSCAP];
  __shared__ float lz[LDSCAP];
  __shared__ alignas(16) u64 pk[2][NW];
  __shared__ int wtot[NW];
  const int b = blockIdx.x;
  const int t = threadIdx.x;
  const int lane = t & 63, w = t >> 6;
  const float* pcb = pc + (size_t)b * NN * 3;
  const float* o0 = obj + (size_t)b * 2 * NN;
  const float* o1 = o0 + NN;
  const float* gb = grasp + (size_t)b * NN;
  float4* fpsXyzb = fpsXyz + (size_t)b * MM;
  float4* cxg = cxyz_g + (size_t)b * NN;

  // ---- pass 1: validity bits + per-wave counts ----
  const int SPAN = 2500;  // 8 waves * 2500 = 20000
  const int wstart = w * SPAN;
  u64 vmask = 0;  // 40 group bits
  int cnt = 0;
#pragma unroll
  for (int g = 0; g < 40; ++g) {
    int off = g * 64 + lane;
    bool v = false;
    if (off < SPAN) {
      int i = wstart + off;
      // argmax(axis=1)==1  <=>  o1 > o0 strictly (argmax picks first max)
      v = (o1[i] > o0[i]) && (gb[i] > GTHR);
    }
    u64 bal = __ballot(v);
    if (v) vmask |= (1ull << g);
    cnt += (int)__popcll(bal);
  }
  if (lane == 0) wtot[w] = cnt;
  __syncthreads();
  int base = 0, nv_ = 0;
#pragma unroll
  for (int k = 0; k < NW; ++k) {
    int c = wtot[k];
    if (k < w) base += c;
    nv_ += c;
  }
  const bool useg = (nv_ > LDSCAP);
  // ---- pass 2: scatter compacted coords ----
#pragma unroll
  for (int g = 0; g < 40; ++g) {
    bool v = (vmask >> g) & 1ull;
    u64 bal = __ballot(v);
    if (v) {
      int i = wstart + g * 64 + lane;
      float xx = pcb[3 * i], yy = pcb[3 * i + 1], zz = pcb[3 * i + 2];
      int pos = base + (int)__popcll(bal & ((1ull << lane) - 1ull));
      if (pos < LDSCAP) { lxy[pos] = make_float2(xx, yy); lz[pos] = zz; }
      if (useg) cxg[pos] = make_float4(xx, yy, zz, 0.f);
    }
    base += (int)__popcll(bal);
  }
  __syncthreads();

  if (nv_ == 0) {  // reference: argmax over all -inf = index 0 every step
    float4 p0 = make_float4(pcb[0], pcb[1], pcb[2], 0.f);
    for (int r = t; r < MM; r += FPS_T) fpsXyzb[r] = p0;
    return;
  }
  int slots = (nv_ + FPS_T - 1) / FPS_T;
  if (slots <= 4)       fps_lds<4>(nv_, lxy, lz, fpsXyzb, pk);
  else if (slots <= 8)  fps_lds<8>(nv_, lxy, lz, fpsXyzb, pk);
  else if (slots <= 9)  fps_lds<9>(nv_, lxy, lz, fpsXyzb, pk);
  else if (slots <= 10) fps_lds<10>(nv_, lxy, lz, fpsXyzb, pk);
  else fps_fallback(nv_, cxg, fpsXyzb, mindg + (size_t)b * NN, pk);
}

// ---------------------------------------------------------------------------
// three_nn (8 queries per 256-thread block) + inverse-distance weights
// ---------------------------------------------------------------------------
__device__ __forceinline__ bool nn_before(float ad, int ai, float bd, int bi) {
  return (ad < bd) || (ad == bd && ai < bi);  // stable ascending (top_k)
}

__device__ __forceinline__ void merge3(float* ad, int* ai,
                                       float b0, float b1, float b2,
                                       int j0, int j1, int j2) {
  bool c0 = nn_before(ad[0], ai[0], b0, j0);
  float r0d = c0 ? ad[0] : b0; int r0i = c0 ? ai[0] : j0;
  float Xd = c0 ? b0 : ad[0];  int Xi = c0 ? j0 : ai[0];
  bool c1 = nn_before(ad[1], ai[1], b1, j1);
  float Yd = c1 ? ad[1] : b1;  int Yi = c1 ? ai[1] : j1;
  bool c2 = nn_before(Xd, Xi, Yd, Yi);
  float r1d = c2 ? Xd : Yd;    int r1i = c2 ? Xi : Yi;
  float Wd = c2 ? Yd : Xd;     int Wi = c2 ? Yi : Xi;
  bool c3 = nn_before(ad[2], ai[2], b2, j2);
  float Vd = c3 ? ad[2] : b2;  int Vi = c3 ? ai[2] : j2;
  bool c4 = nn_before(Wd, Wi, Vd, Vi);
  float r2d = c4 ? Wd : Vd;    int r2i = c4 ? Wi : Vi;
  ad[0] = r0d; ad[1] = r1d; ad[2] = r2d;
  ai[0] = r0i; ai[1] = r1i; ai[2] = r2i;
}

__global__ void three_nn_kernel(const float* __restrict__ pc,
                                const float4* __restrict__ fpsXyz,
                                int* __restrict__ idx3,
                                float* __restrict__ w3) {
  const int blk = blockIdx.x;
  const int b = blk / (MM / QB);
  const int qbase = (blk % (MM / QB)) * QB;
  const int t = threadIdx.x;
  const int lane = t & 63, w = t >> 6;
  const float* pcb = pc + (size_t)b * NN * 3;
  float qx[QB], qy[QB], qz[QB];
#pragma unroll
  for (int qq = 0; qq < QB; ++qq) {
    float4 p = fpsXyz[(size_t)b * MM + qbase + qq];
    qx[qq] = p.x; qy[qq] = p.y; qz[qq] = p.z;
  }
  float qd[QB][3]; int qi[QB][3];
#pragma unroll
  for (int qq = 0; qq < QB; ++qq)
#pragma unroll
    for (int k = 0; k < 3; ++k) { qd[qq][k] = INFF; qi[qq][k] = 0x7fffffff; }

  const int nchunk = (NN + 255) / 256;
  for (int c = 0; c < nchunk; ++c) {
    int i = c * 256 + t;
    if (i < NN) {
      float pxx = pcb[3 * i], pyy = pcb[3 * i + 1], pzz = pcb[3 * i + 2];
#pragma unroll
      for (int qq = 0; qq < QB; ++qq) {
        float dx = pxx - qx[qq], dy = pyy - qy[qq], dz = pzz - qz[qq];
        float d = fmaf(dz, dz, fmaf(dy, dy, dx * dx));
        if (d < qd[qq][2]) {
          bool lt0 = d < qd[qq][0], lt1 = d < qd[qq][1];
          qd[qq][2] = lt1 ? qd[qq][1] : d;  qi[qq][2] = lt1 ? qi[qq][1] : i;
          float nd1 = lt0 ? qd[qq][0] : (lt1 ? d : qd[qq][1]);
          int   ni1 = lt0 ? qi[qq][0] : (lt1 ? i : qi[qq][1]);
          qd[qq][1] = nd1; qi[qq][1] = ni1;
          qd[qq][0] = lt0 ? d : qd[qq][0];  qi[qq][0] = lt0 ? i : qi[qq][0];
        }
      }
    }
  }
#pragma unroll
  for (int off = 32; off; off >>= 1) {
#pragma unroll
    for (int qq = 0; qq < QB; ++qq) {
      float bd0 = __shfl_xor(qd[qq][0], off);
      float bd1 = __shfl_xor(qd[qq][1], off);
      float bd2 = __shfl_xor(qd[qq][2], off);
      int bi0 = __shfl_xor(qi[qq][0], off);
      int bi1 = __shfl_xor(qi[qq][1], off);
      int bi2 = __shfl_xor(qi[qq][2], off);
      merge3(qd[qq], qi[qq], bd0, bd1, bd2, bi0, bi1, bi2);
    }
  }
  __shared__ float smd[4][QB][3];
  __shared__ int smi[4][QB][3];
  if (lane == 0) {
#pragma unroll
    for (int qq = 0; qq < QB; ++qq)
#pragma unroll
      for (int k = 0; k < 3; ++k) { smd[w][qq][k] = qd[qq][k]; smi[w][qq][k] = qi[qq][k]; }
  }
  __syncthreads();
  if (t < QB) {
    int qq = t;
    float fd[3]; int fi[3];
#pragma unroll
    for (int k = 0; k < 3; ++k) { fd[k] = smd[0][qq][k]; fi[k] = smi[0][qq][k]; }
#pragma unroll
    for (int ww = 1; ww < 4; ++ww)
      merge3(fd, fi, smd[ww][qq][0], smd[ww][qq][1], smd[ww][qq][2],
             smi[ww][qq][0], smi[ww][qq][1], smi[ww][qq][2]);
    float wa = 1.f / (sqrtf(fmaxf(fd[0], 0.f)) + 1e-8f);
    float wb = 1.f / (sqrtf(fmaxf(fd[1], 0.f)) + 1e-8f);
    float wc = 1.f / (sqrtf(fmaxf(fd[2], 0.f)) + 1e-8f);
    float s = wa + wb + wc;
    size_t base3 = ((size_t)b * MM + qbase + qq) * 3;
    w3[base3] = wa / s; w3[base3 + 1] = wb / s; w3[base3 + 2] = wc / s;
    idx3[base3] = fi[0]; idx3[base3 + 1] = fi[1]; idx3[base3 + 2] = fi[2];
  }
}

// ---------------------------------------------------------------------------
// three_interpolate (one block per (b,c) feature row)
// ---------------------------------------------------------------------------
__global__ void interp_kernel(const float* __restrict__ seed,
                              const int* __restrict__ idx3,
                              const float* __restrict__ w3,
                              float* __restrict__ out) {
  const int blk = blockIdx.x;
  const int b = blk / CC;
  const int c = blk % CC;
  const float* row = seed + ((size_t)b * CC + c) * NN;
  const int t = threadIdx.x;
#pragma unroll
  for (int u = 0; u < MM / 256; ++u) {
    int m = u * 256 + t;
    size_t base3 = ((size_t)b * MM + m) * 3;
    int i0 = idx3[base3], i1 = idx3[base3 + 1], i2 = idx3[base3 + 2];
    float w0 = w3[base3], w1 = w3[base3 + 1], w2 = w3[base3 + 2];
    float v = fmaf(w2, row[i2], fmaf(w1, row[i1], w0 * row[i0]));
    out[((size_t)b * CC + c) * MM + m] = v;
  }
}

// ---------------------------------------------------------------------------
extern "C" void kernel_launch(void* const* d_in, const int* in_sizes, int n_in,
                              void* d_out, int out_size, void* d_ws,
                              size_t ws_size, hipStream_t stream) {
  (void)in_sizes; (void)n_in; (void)out_size; (void)ws_size;
  const float* pc = (const float*)d_in[0];     // (B,N,3)
  const float* seed = (const float*)d_in[1];   // (B,C,N)
  const float* obj = (const float*)d_in[2];    // (B,2,N)
  const float* grasp = (const float*)d_in[3];  // (B,N)
  float* out = (float*)d_out;                  // (B,C,M)

  char* p = (char*)d_ws;
  float4* cxyz = (float4*)p;   p += sizeof(float4) * BB * NN;
  float4* fpsXyz = (float4*)p; p += sizeof(float4) * BB * MM;
  int* idx3 = (int*)p;         p += sizeof(int) * BB * MM * 3;
  float* w3 = (float*)p;       p += sizeof(float) * BB * MM * 3;
  float* mindg = (float*)p;    p += sizeof(float) * BB * NN;

  hipLaunchKernelGGL(fps_kernel, dim3(BB), dim3(FPS_T), 0, stream,
                     pc, obj, grasp, fpsXyz, cxyz, mindg);
  hipLaunchKernelGGL(three_nn_kernel, dim3(BB * MM / QB), dim3(256), 0, stream,
                     pc, fpsXyz, idx3, w3);
  hipLaunchKernelGGL(interp_kernel, dim3(BB * CC), dim3(256), 0, stream,
                     seed, idx3, w3, out);
}